// Round 16
// baseline (266.519 us; speedup 1.0000x reference)
//
#include <hip/hip_runtime.h>

// Separable 3D Gaussian blur (sigma=1, truncate=3 -> 7 taps), SAME zero padding.
// (N=2, D=160, H=160, W=160, C=4) float32 == float4 over C.
// Round 16: split-phase halves. Block = 2 independent 16(H)x16(W) sub-tiles
// (half A: tid<128, half B: tid>=128) running the R11 2-barrier slice
// pipeline OFFSET by one phase:
//   phase1: A=W-blur (LDS-heavy)          B=H-blur+out+commit+PREF (VALU/VMEM)
//   phase2: A=H-blur+out+commit+PREF      B=W-blur
// -> LDS-pipe work and VALU work are co-resident on the CU at all times
//    instead of serialized by block-wide phases.
// Hazards: every same-buffer write/read pair separated by >=1 lgkm barrier
// (audited per half; single-buffered raw+wb per half).
// Kept from R10/R11: all-f32, XCD-chunked bijective swizzle, lgkmcnt-only
// barriers, prefetch-1, launch_bounds(256,4). LDS 28.2KB -> 5 blocks/CU;
// CHUNK=10 -> 1600 blocks = 6.25/CU.

#define THT 16
#define TWT 16             // per half
#define CHUNK 10
#define NS (CHUNK + 6)     // 16 slices per block
#define DIM 160
#define SLICE (DIM * DIM)
#define HALON (22 * 22)    // 484 staged f4 per half per slice
#define NBLK 1600          // 2(n) * 10(th) * 5(tw2) * 16(chunk) = 8 XCDs x 200

#define W0 0.004433048f
#define W1 0.054005582f
#define W2 0.242036229f
#define W3 0.399050300f

__device__ __forceinline__ float4 blur7(float4 a0, float4 a1, float4 a2, float4 a3,
                                        float4 a4, float4 a5, float4 a6) {
    float4 r;
    r.x = W0 * (a0.x + a6.x) + W1 * (a1.x + a5.x) + W2 * (a2.x + a4.x) + W3 * a3.x;
    r.y = W0 * (a0.y + a6.y) + W1 * (a1.y + a5.y) + W2 * (a2.y + a4.y) + W3 * a3.y;
    r.z = W0 * (a0.z + a6.z) + W1 * (a1.z + a5.z) + W2 * (a2.z + a4.z) + W3 * a3.z;
    r.w = W0 * (a0.w + a6.w) + W1 * (a1.w + a5.w) + W2 * (a2.w + a4.w) + W3 * a3.w;
    return r;
}

// Workgroup barrier with LDS visibility but NO vmcnt(0) drain.
__device__ __forceinline__ void lds_barrier() {
    asm volatile("s_waitcnt lgkmcnt(0)" ::: "memory");
    __builtin_amdgcn_s_barrier();
}

__global__ __launch_bounds__(256, 4)
void gauss3d_fused(const float4* __restrict__ in, float4* __restrict__ out) {
    // XCD-chunked bijective swizzle: 1600 = 8 * 200 exactly.
    int work = (blockIdx.x & 7) * (NBLK / 8) + (blockIdx.x >> 3);
    const int tw2   = work % 5;             work /= 5;    // pair of W-tiles
    const int th    = work % 10;            work /= 10;
    const int chunk = work % (DIM / CHUNK); work /= (DIM / CHUNK); // 16
    const int n     = work;                                        // 2

    const int h0 = th * THT;
    const int d0 = chunk * CHUNK;

    __shared__ float4 rawA[22][23], rawB[22][23];  // halo 22x22 f32, +1 pad
    __shared__ float4 wbA[22][17],  wbB[22][17];   // W-blurred 22x16, +1 pad

    const int tid = threadIdx.x;
    const int hB   = tid >> 7;       // 0 = half A (waves 0-1), 1 = half B
    const int ltid = tid & 127;

    float4 (*raw)[23] = hB ? rawB : rawA;
    float4 (*wb)[17]  = hB ? wbB  : wbA;
    const int w0 = (tw2 * 2 + hB) * TWT;

    const size_t nbase = (size_t)n * DIM * SLICE;
    const float4 z = make_float4(0.f, 0.f, 0.f, 0.f);

    // ---- stage constants: 484 halo f4 over 128 threads (<=4 slots) ----
    int  soff[4], rbidx[4];
    bool sok[4];
    #pragma unroll
    for (int s = 0; s < 4; ++s) {
        const int i = ltid + 128 * s;
        const bool has = (i < HALON);
        const int rr = has ? (i / 22) : 0, cc = has ? (i % 22) : 0;
        const int gh = h0 + rr - 3, gw = w0 + cc - 3;
        const bool ok = has && gh >= 0 && gh < DIM && gw >= 0 && gw < DIM;
        soff[s]  = ok ? (gh * DIM + gw) : 0;
        sok[s]   = ok;
        rbidx[s] = rr * 23 + cc;
    }
    const bool shas3 = (ltid + 384 < HALON);

    // ---- W-blur workers: 88 = 22 rows x 4 groups of 4 cols ----
    const bool isW = (ltid < 88);
    const int wr  = ltid >> 2;       // 0..21
    const int wc0 = (ltid & 3) * 4;  // 0,4,8,12

    // ---- H-blur: 128 threads = 8 H-pairs x 16 cols ----
    const int hp = ltid >> 4;        // 0..7 -> rows 2hp, 2hp+1
    const int lw = ltid & 15;        // 0..15

    float4 pf0, pf1, pf2, pf3;
    float4 a0 = z, a1 = z, a2 = z, a3 = z, a4 = z, a5 = z, a6 = z;
    float4 b0 = z, b1 = z, b2 = z, b3 = z, b4 = z, b5 = z, b6 = z;

#define PREF(DSL)                                                            \
    do {                                                                     \
        const int _d = (DSL);                                                \
        const bool _inr = (_d >= 0) && (_d < DIM);                           \
        const float4* _s = in + nbase + (size_t)(_inr ? _d : 0) * SLICE;     \
        pf0 = (_inr && sok[0]) ? _s[soff[0]] : z;                            \
        pf1 = (_inr && sok[1]) ? _s[soff[1]] : z;                            \
        pf2 = (_inr && sok[2]) ? _s[soff[2]] : z;                            \
        pf3 = (_inr && sok[3]) ? _s[soff[3]] : z;                            \
    } while (0)

#define COMMIT()                                                             \
    do {                                                                     \
        float4* rb = &raw[0][0];                                             \
        rb[rbidx[0]] = pf0;                                                  \
        rb[rbidx[1]] = pf1;                                                  \
        rb[rbidx[2]] = pf2;                                                  \
        if (shas3) rb[rbidx[3]] = pf3;                                       \
    } while (0)

#define WPH()                                                                \
    do {                                                                     \
        if (isW) {                                                           \
            float4 rv0 = raw[wr][wc0 + 0];                                   \
            float4 rv1 = raw[wr][wc0 + 1];                                   \
            float4 rv2 = raw[wr][wc0 + 2];                                   \
            float4 rv3 = raw[wr][wc0 + 3];                                   \
            float4 rv4 = raw[wr][wc0 + 4];                                   \
            float4 rv5 = raw[wr][wc0 + 5];                                   \
            float4 rv6 = raw[wr][wc0 + 6];                                   \
            float4 rv7 = raw[wr][wc0 + 7];                                   \
            float4 rv8 = raw[wr][wc0 + 8];                                   \
            float4 rv9 = raw[wr][wc0 + 9];                                   \
            wb[wr][wc0 + 0] = blur7(rv0, rv1, rv2, rv3, rv4, rv5, rv6);      \
            wb[wr][wc0 + 1] = blur7(rv1, rv2, rv3, rv4, rv5, rv6, rv7);      \
            wb[wr][wc0 + 2] = blur7(rv2, rv3, rv4, rv5, rv6, rv7, rv8);      \
            wb[wr][wc0 + 3] = blur7(rv3, rv4, rv5, rv6, rv7, rv8, rv9);      \
        }                                                                    \
    } while (0)

#define HPH(SJ)                                                              \
    do {                                                                     \
        float4 c0 = wb[2 * hp + 0][lw];                                      \
        float4 c1 = wb[2 * hp + 1][lw];                                      \
        float4 c2 = wb[2 * hp + 2][lw];                                      \
        float4 c3 = wb[2 * hp + 3][lw];                                      \
        float4 c4 = wb[2 * hp + 4][lw];                                      \
        float4 c5 = wb[2 * hp + 5][lw];                                      \
        float4 c6 = wb[2 * hp + 6][lw];                                      \
        float4 c7 = wb[2 * hp + 7][lw];                                      \
        float4 va = blur7(c0, c1, c2, c3, c4, c5, c6);                       \
        float4 vb = blur7(c1, c2, c3, c4, c5, c6, c7);                       \
        a0 = a1; a1 = a2; a2 = a3; a3 = a4; a4 = a5; a5 = a6; a6 = va;       \
        b0 = b1; b1 = b2; b2 = b3; b3 = b4; b4 = b5; b5 = b6; b6 = vb;       \
        const int dout = (SJ) - 3;                                           \
        if (dout >= d0) {                                                    \
            float4 oa = blur7(a0, a1, a2, a3, a4, a5, a6);                   \
            float4 ob = blur7(b0, b1, b2, b3, b4, b5, b6);                   \
            const size_t base = nbase + (size_t)dout * SLICE;                \
            out[base + (size_t)(h0 + 2 * hp + 0) * DIM + (w0 + lw)] = oa;    \
            out[base + (size_t)(h0 + 2 * hp + 1) * DIM + (w0 + lw)] = ob;    \
        }                                                                    \
    } while (0)

    // ---- prologue ----
    PREF(d0 - 3);                 // both halves load slice s0
    if (!hB) {                    // A commits s0 now; first W reads it after
        COMMIT();                 // barrier1 of k=0.
        PREF(d0 - 2);             // A holds s1 for its phase2 commit
    }                             // B holds s0 for its phase1 commit

    for (int k = 0; k <= NS; ++k) {
        const int sk = d0 - 3 + k;

        lds_barrier();  // phase1 start
        if (!hB) {
            if (k < NS) WPH();                       // A: W(s_k)
        } else {
            if (k >= 1) HPH(sk - 1);                 // B: H(s_{k-1}) + out
            if (k < NS) {
                COMMIT();                            // B: raw <- s_k
                if (k + 1 < NS) PREF(sk + 1);
            }
        }

        lds_barrier();  // phase2 start
        if (!hB) {
            if (k < NS) HPH(sk);                     // A: H(s_k) + out
            if (k + 1 < NS) {
                COMMIT();                            // A: raw <- s_{k+1}
                if (k + 2 < NS) PREF(sk + 2);
            }
        } else {
            if (k < NS) WPH();                       // B: W(s_k)
        }
    }
#undef PREF
#undef COMMIT
#undef WPH
#undef HPH
}

extern "C" void kernel_launch(void* const* d_in, const int* in_sizes, int n_in,
                              void* d_out, int out_size, void* d_ws, size_t ws_size,
                              hipStream_t stream) {
    const float4* in = (const float4*)d_in[0];
    float4* out = (float4*)d_out;
    gauss3d_fused<<<NBLK, 256, 0, stream>>>(in, out);
}

// Round 17
// 100.454 us; speedup vs baseline: 2.6531x; 2.6531x over previous
//
#include <hip/hip_runtime.h>

// Separable 3D Gaussian blur (sigma=1, truncate=3 -> 7 taps), SAME zero padding.
// (N=2, D=160, H=160, W=160, C=4) float32 == float4 over C.
// Round 17 = R11 skeleton + async staging via __builtin_amdgcn_global_load_lds:
//  - raw is a FLAT unpadded [22*38] f4 tile (double-buffered): gload_lds writes
//    wave-uniform base + lane*16 -> flat index i = tid + 256*slot, matching the
//    stage mapping exactly. No register prefetch, no ds_write commit phase,
//    no vmcnt-implicit stall at commit.
//  - boundary: !ok lanes pre-zeroed once (never overwritten: gloads are
//    exec-masked to ok); D-OOB slices write zeros via ds_write (chunk edges).
//  - counted wait: the 4 staged loads are always the OLDEST outstanding vmem;
//    after outputs start, 2 stores trail them -> s_waitcnt vmcnt(2) drains
//    exactly the loads; vmcnt(0) before first store exists.
// Kept: tile 16x32, CHUNK=16 -> 1000 blocks = 8 XCDs x 125 (bijective swizzle),
// 176 W-workers x (10 reads -> 4 wb outputs), H-pairs + dual 7-deep D-rings,
// 2 lgkmcnt-only barriers, launch_bounds(256,4). Spill canary: WRITE ~136MB.

#define THT 16
#define TWT 32
#define CHUNK 16
#define NS (CHUNK + 6)      // 22 slices per block
#define DIM 160
#define SLICE (DIM * DIM)
#define RAWN (22 * 38)      // 836 staged f4 per slice
#define RAWP 864            // padded per-buffer f4 count
#define NBLK 1000           // 2*10*5*10 = 8 XCDs x 125

#define W0 0.004433048f
#define W1 0.054005582f
#define W2 0.242036229f
#define W3 0.399050300f

__device__ __forceinline__ float4 blur7(float4 a0, float4 a1, float4 a2, float4 a3,
                                        float4 a4, float4 a5, float4 a6) {
    float4 r;
    r.x = W0 * (a0.x + a6.x) + W1 * (a1.x + a5.x) + W2 * (a2.x + a4.x) + W3 * a3.x;
    r.y = W0 * (a0.y + a6.y) + W1 * (a1.y + a5.y) + W2 * (a2.y + a4.y) + W3 * a3.y;
    r.z = W0 * (a0.z + a6.z) + W1 * (a1.z + a5.z) + W2 * (a2.z + a4.z) + W3 * a3.z;
    r.w = W0 * (a0.w + a6.w) + W1 * (a1.w + a5.w) + W2 * (a2.w + a4.w) + W3 * a3.w;
    return r;
}

typedef __attribute__((address_space(3))) void lds_void_t;
typedef const __attribute__((address_space(1))) void gbl_void_t;

// HBM -> LDS direct, 16B per lane at (wave-uniform l) + lane*16.
__device__ __forceinline__ void gload16(const float4* g, float4* l) {
    __builtin_amdgcn_global_load_lds((gbl_void_t*)g, (lds_void_t*)l, 16, 0, 0);
}

// Workgroup barrier with LDS visibility but NO vmcnt(0) drain.
__device__ __forceinline__ void lds_barrier() {
    asm volatile("s_waitcnt lgkmcnt(0)" ::: "memory");
    __builtin_amdgcn_s_barrier();
}

__global__ __launch_bounds__(256, 4)
void gauss3d_fused(const float4* __restrict__ in, float4* __restrict__ out) {
    // XCD-chunked bijective swizzle: 1000 = 8 * 125 exactly.
    int work = (blockIdx.x & 7) * (NBLK / 8) + (blockIdx.x >> 3);
    const int tw    = work % (DIM / TWT);   work /= (DIM / TWT);   // 5
    const int th    = work % (DIM / THT);   work /= (DIM / THT);   // 10
    const int chunk = work % (DIM / CHUNK); work /= (DIM / CHUNK); // 10
    const int n     = work;                                        // 2

    const int h0 = th * THT;
    const int w0 = tw * TWT;
    const int d0 = chunk * CHUNK;

    __shared__ float4 raw[2][RAWP];   // flat 22x38 halo f4, dbuf, UNPADDED rows
    __shared__ float4 wb[22][33];     // W-blurred 22x32, +1 col pad

    const int tid = threadIdx.x;
    const size_t nbase = (size_t)n * DIM * SLICE;
    const float4 z = make_float4(0.f, 0.f, 0.f, 0.f);

    // ---- stage constants: flat i = tid + 256*slot -> (rr,cc) in 22x38 ----
    int  soff[4];
    bool sok[4], shas[4];
    #pragma unroll
    for (int s = 0; s < 4; ++s) {
        const int i = tid + 256 * s;
        const bool has = (i < RAWN);
        const int rr = has ? (i / 38) : 0, cc = has ? (i % 38) : 0;
        const int gh = h0 + rr - 3, gw = w0 + cc - 3;
        const bool ok = has && gh >= 0 && gh < DIM && gw >= 0 && gw < DIM;
        soff[s] = ok ? (gh * DIM + gw) : 0;
        sok[s]  = ok;
        shas[s] = has;
    }

    // pre-zero slots whose lane is in-tile but outside the image (static mask;
    // gloads are exec-masked to ok so these are never overwritten)
    #pragma unroll
    for (int s = 0; s < 4; ++s) {
        if (shas[s] && !sok[s]) {
            raw[0][tid + 256 * s] = z;
            raw[1][tid + 256 * s] = z;
        }
    }

    // ---- W-blur workers: 176 = 22 rows x 8 groups of 4 cols ----
    const bool isW = (tid < 176);
    const int wr  = tid >> 3;        // 0..21
    const int wc0 = (tid & 7) * 4;   // 0,4,...,28
    const int wbase = wr * 38 + wc0; // flat raw index of first read

    // ---- H-blur: 256 threads = 8 H-pairs x 32 cols ----
    const int hp = tid >> 5;         // 0..7 -> output rows 2hp, 2hp+1
    const int lw = tid & 31;         // 0..31

    float4 a0 = z, a1 = z, a2 = z, a3 = z, a4 = z, a5 = z, a6 = z;
    float4 b0 = z, b1 = z, b2 = z, b3 = z, b4 = z, b5 = z, b6 = z;

    const int wavebase = tid & ~63;  // wave-uniform lane-group base

#define STAGE(BUF, DSL)                                                      \
    do {                                                                     \
        const int _d = (DSL);                                                \
        if (_d >= 0 && _d < DIM) {                                           \
            const float4* _g = in + nbase + (size_t)_d * SLICE;              \
            float4* _lw = &raw[BUF][wavebase];                               \
            if (sok[0]) gload16(_g + soff[0], _lw + 0);                      \
            if (sok[1]) gload16(_g + soff[1], _lw + 256);                    \
            if (sok[2]) gload16(_g + soff[2], _lw + 512);                    \
            if (sok[3]) gload16(_g + soff[3], _lw + 768);                    \
        } else {                                                             \
            if (sok[0]) raw[BUF][tid + 0]   = z;                             \
            if (sok[1]) raw[BUF][tid + 256] = z;                             \
            if (sok[2]) raw[BUF][tid + 512] = z;                             \
            if (sok[3]) raw[BUF][tid + 768] = z;                             \
        }                                                                    \
    } while (0)

    // prologue: stage first slice into buffer 0
    STAGE(0, d0 - 3);

    for (int k = 0; k < NS; ++k) {
        const int din = d0 - 3 + k;
        const int buf = k & 1;

        // drain the 4 staged loads for raw[buf] (oldest outstanding vmem);
        // after outputs begin, 2 stores trail them -> vmcnt(2) suffices.
        if (k <= 6) { asm volatile("s_waitcnt vmcnt(0)" ::: "memory"); }
        else        { asm volatile("s_waitcnt vmcnt(2)" ::: "memory"); }

        lds_barrier();  // A: raw[buf] visible to all; prev H reads of wb and
                        //    prev W reads of raw[buf^1] drained.

        // issue next slice's async loads into the other buffer; they have the
        // whole W+H phase (plus barrier) to land.
        if (k + 1 < NS) STAGE(buf ^ 1, din + 1);

        // W-blur: 176 workers, 10 flat raw reads -> 4 wb outputs each
        if (isW) {
            const float4* rb = &raw[buf][0];
            float4 rv0 = rb[wbase + 0];
            float4 rv1 = rb[wbase + 1];
            float4 rv2 = rb[wbase + 2];
            float4 rv3 = rb[wbase + 3];
            float4 rv4 = rb[wbase + 4];
            float4 rv5 = rb[wbase + 5];
            float4 rv6 = rb[wbase + 6];
            float4 rv7 = rb[wbase + 7];
            float4 rv8 = rb[wbase + 8];
            float4 rv9 = rb[wbase + 9];
            wb[wr][wc0 + 0] = blur7(rv0, rv1, rv2, rv3, rv4, rv5, rv6);
            wb[wr][wc0 + 1] = blur7(rv1, rv2, rv3, rv4, rv5, rv6, rv7);
            wb[wr][wc0 + 2] = blur7(rv2, rv3, rv4, rv5, rv6, rv7, rv8);
            wb[wr][wc0 + 3] = blur7(rv3, rv4, rv5, rv6, rv7, rv8, rv9);
        }

        lds_barrier();  // B: wb visible; raw[buf] reads drained (STAGE into
                        //    buf^1 does not conflict with raw[buf]).

        // H-blur pair: 8 wb reads -> 2 new ring values
        {
            float4 c0 = wb[2 * hp + 0][lw];
            float4 c1 = wb[2 * hp + 1][lw];
            float4 c2 = wb[2 * hp + 2][lw];
            float4 c3 = wb[2 * hp + 3][lw];
            float4 c4 = wb[2 * hp + 4][lw];
            float4 c5 = wb[2 * hp + 5][lw];
            float4 c6 = wb[2 * hp + 6][lw];
            float4 c7 = wb[2 * hp + 7][lw];
            float4 va = blur7(c0, c1, c2, c3, c4, c5, c6);
            float4 vb = blur7(c1, c2, c3, c4, c5, c6, c7);
            a0 = a1; a1 = a2; a2 = a3; a3 = a4; a4 = a5; a5 = a6; a6 = va;
            b0 = b1; b1 = b2; b2 = b3; b3 = b4; b4 = b5; b5 = b6; b6 = vb;
        }

        // emit dout = din - 3 once the ring is primed (k >= 6)
        if (k >= 6) {
            const int dout = din - 3;
            float4 oa = blur7(a0, a1, a2, a3, a4, a5, a6);
            float4 ob = blur7(b0, b1, b2, b3, b4, b5, b6);
            const size_t base = nbase + (size_t)dout * SLICE;
            out[base + (size_t)(h0 + 2 * hp + 0) * DIM + (w0 + lw)] = oa;
            out[base + (size_t)(h0 + 2 * hp + 1) * DIM + (w0 + lw)] = ob;
        }
    }
#undef STAGE
}

extern "C" void kernel_launch(void* const* d_in, const int* in_sizes, int n_in,
                              void* d_out, int out_size, void* d_ws, size_t ws_size,
                              hipStream_t stream) {
    const float4* in = (const float4*)d_in[0];
    float4* out = (float4*)d_out;
    gauss3d_fused<<<NBLK, 256, 0, stream>>>(in, out);
}

// Round 18
// 70.408 us; speedup vs baseline: 3.7853x; 1.4267x over previous
//
#include <hip/hip_runtime.h>

// Separable 3D Gaussian blur (sigma=1, truncate=3 -> 7 taps), SAME zero padding.
// (N=2, D=160, H=160, W=160, C=4) float32 == float4 over C.
// Round 18: ZERO-BARRIER wave-autonomous tiles. Each wave owns a private
// 16(H)x16(W) tile (own raw/wb LDS region, own D-chunk stream). All LDS
// hazards are intra-wave -> handled by in-order wave execution + compiler
// lgkmcnt waits. NO s_barrier anywhere, no inline asm -> compiler is free to
// software-pipeline the slice loop across phases.
// Tests the hypothesis that the ~79us plateau (R10/R11, all pipes <=40%) is
// block-wide barrier phase-alignment, not any throughput limit.
//  - 2000 waves = 2n x 10th x 10tw x 10chunk (CHUNK=16); 500 blocks of 4 waves
//  - LDS 4 x (raw 22x23 + wb 22x17) f4 = 56.3 KB -> 2 blocks/CU (8 waves/CU)
//  - 4 D-rings/lane (4 output rows) = 112 VGPR; launch_bounds(256,2) cap 256
//  - register prefetch 1 slice ahead (8 f4); stage->W->H all intra-wave
//  - bijective XCD swizzle for 500 blocks (q=62, r=4)

#define THT 16
#define TWT 16
#define CHUNK 16
#define NS (CHUNK + 6)      // 22 slices per wave
#define DIM 160
#define SLICE (DIM * DIM)
#define HALON (22 * 22)     // 484 staged f4 per slice
#define NBLK 500

#define W0 0.004433048f
#define W1 0.054005582f
#define W2 0.242036229f
#define W3 0.399050300f

__device__ __forceinline__ float4 blur7(float4 a0, float4 a1, float4 a2, float4 a3,
                                        float4 a4, float4 a5, float4 a6) {
    float4 r;
    r.x = W0 * (a0.x + a6.x) + W1 * (a1.x + a5.x) + W2 * (a2.x + a4.x) + W3 * a3.x;
    r.y = W0 * (a0.y + a6.y) + W1 * (a1.y + a5.y) + W2 * (a2.y + a4.y) + W3 * a3.y;
    r.z = W0 * (a0.z + a6.z) + W1 * (a1.z + a5.z) + W2 * (a2.z + a4.z) + W3 * a3.z;
    r.w = W0 * (a0.w + a6.w) + W1 * (a1.w + a5.w) + W2 * (a2.w + a4.w) + W3 * a3.w;
    return r;
}

__global__ __launch_bounds__(256, 2)
void gauss3d_fused(const float4* __restrict__ in, float4* __restrict__ out) {
    // bijective XCD-chunked swizzle for 500 blocks: q=62, r=4
    const int bid = blockIdx.x;
    const int xcd = bid & 7;
    const int bix = bid >> 3;
    const int swz = (xcd < 4 ? xcd * 63 : 252 + (xcd - 4) * 62) + bix;

    const int tid  = threadIdx.x;
    const int wv   = tid >> 6;      // wave id in block (0..3)
    const int lane = tid & 63;

    int wid = swz * 4 + wv;         // global wave-tile id, 0..1999
    const int tw    = wid % 10;  wid /= 10;
    const int th    = wid % 10;  wid /= 10;
    const int chunk = wid % 10;  wid /= 10;
    const int n     = wid;          // 0..1

    const int h0 = th * THT;
    const int w0 = tw * TWT;
    const int d0 = chunk * CHUNK;

    __shared__ float4 raw[4][22][23];   // per-wave halo tile, +1 col pad
    __shared__ float4 wb[4][22][17];    // per-wave W-blurred tile, +1 col pad
    float4 (* const rawW)[23] = raw[wv];
    float4 (* const wbW)[17]  = wb[wv];

    const size_t nbase = (size_t)n * DIM * SLICE;
    const float4 z = make_float4(0.f, 0.f, 0.f, 0.f);

    // ---- stage constants: 484 halo f4 over 64 lanes (8 slots) ----
    int  soff[8], ridx[8];
    bool sok[8];
    #pragma unroll
    for (int s = 0; s < 8; ++s) {
        const int j = lane + 64 * s;
        const bool has = (j < HALON);
        const int rr = has ? (j / 22) : 0, cc = has ? (j % 22) : 0;
        const int gh = h0 + rr - 3, gw = w0 + cc - 3;
        const bool ok = has && gh >= 0 && gh < DIM && gw >= 0 && gw < DIM;
        soff[s] = ok ? (gh * DIM + gw) : 0;
        sok[s]  = ok;
        ridx[s] = rr * 23 + cc;
    }
    const bool has7 = (lane + 448 < HALON);   // lane < 36

    // ---- W-blur groups: 88 groups of 4 outputs; lane does g=lane and
    //      (lane<24) g=64+lane ----
    const int g1r = lane >> 2, g1c = (lane & 3) * 4;
    const bool hasG2 = (lane < 24);
    const int g2r = (64 + lane) >> 2, g2c = ((64 + lane) & 3) * 4;

    // ---- H-blur: lane = (q = lane>>4 -> rows 4q..4q+3, lw = lane&15) ----
    const int q  = lane >> 4;
    const int lw = lane & 15;

    // 4 D-rings (output rows 4q..4q+3), 7 deep each
    float4 qa0=z,qa1=z,qa2=z,qa3=z,qa4=z,qa5=z,qa6=z;
    float4 qb0=z,qb1=z,qb2=z,qb3=z,qb4=z,qb5=z,qb6=z;
    float4 qc0=z,qc1=z,qc2=z,qc3=z,qc4=z,qc5=z,qc6=z;
    float4 qd0=z,qd1=z,qd2=z,qd3=z,qd4=z,qd5=z,qd6=z;

    float4 pf0, pf1, pf2, pf3, pf4, pf5, pf6, pf7;

#define PREFETCH(DSL)                                                        \
    do {                                                                     \
        const int _d = (DSL);                                                \
        const bool _inr = (_d >= 0) && (_d < DIM);                           \
        const float4* _s = in + nbase + (size_t)(_inr ? _d : 0) * SLICE;     \
        pf0 = (_inr && sok[0]) ? _s[soff[0]] : z;                            \
        pf1 = (_inr && sok[1]) ? _s[soff[1]] : z;                            \
        pf2 = (_inr && sok[2]) ? _s[soff[2]] : z;                            \
        pf3 = (_inr && sok[3]) ? _s[soff[3]] : z;                            \
        pf4 = (_inr && sok[4]) ? _s[soff[4]] : z;                            \
        pf5 = (_inr && sok[5]) ? _s[soff[5]] : z;                            \
        pf6 = (_inr && sok[6]) ? _s[soff[6]] : z;                            \
        pf7 = (_inr && sok[7]) ? _s[soff[7]] : z;                            \
    } while (0)

#define WGRP(R, C0)                                                          \
    do {                                                                     \
        const float4* _rr = &rawW[R][0];                                     \
        float4 v0 = _rr[(C0) + 0];                                           \
        float4 v1 = _rr[(C0) + 1];                                           \
        float4 v2 = _rr[(C0) + 2];                                           \
        float4 v3 = _rr[(C0) + 3];                                           \
        float4 v4 = _rr[(C0) + 4];                                           \
        float4 v5 = _rr[(C0) + 5];                                           \
        float4 v6 = _rr[(C0) + 6];                                           \
        float4 v7 = _rr[(C0) + 7];                                           \
        float4 v8 = _rr[(C0) + 8];                                           \
        float4 v9 = _rr[(C0) + 9];                                           \
        float4* _wr = &wbW[R][0];                                            \
        _wr[(C0) + 0] = blur7(v0, v1, v2, v3, v4, v5, v6);                   \
        _wr[(C0) + 1] = blur7(v1, v2, v3, v4, v5, v6, v7);                   \
        _wr[(C0) + 2] = blur7(v2, v3, v4, v5, v6, v7, v8);                   \
        _wr[(C0) + 3] = blur7(v3, v4, v5, v6, v7, v8, v9);                   \
    } while (0)

    PREFETCH(d0 - 3);

    for (int k = 0; k < NS; ++k) {
        const int din = d0 - 3 + k;

        // 1) commit prefetched slice into this wave's raw tile
        {
            float4* rb = &rawW[0][0];
            rb[ridx[0]] = pf0;
            rb[ridx[1]] = pf1;
            rb[ridx[2]] = pf2;
            rb[ridx[3]] = pf3;
            rb[ridx[4]] = pf4;
            rb[ridx[5]] = pf5;
            rb[ridx[6]] = pf6;
            if (has7) rb[ridx[7]] = pf7;
        }

        // 2) issue next slice's loads (latency hides under W+H phases)
        if (k + 1 < NS) PREFETCH(din + 1);

        // 3) W-blur (intra-wave lgkmcnt orders raw writes -> reads)
        WGRP(g1r, g1c);
        if (hasG2) WGRP(g2r, g2c);

        // 4) H-blur: 10 wb reads -> 4 new ring values (rows 4q..4q+3)
        {
            float4 t0 = wbW[4 * q + 0][lw];
            float4 t1 = wbW[4 * q + 1][lw];
            float4 t2 = wbW[4 * q + 2][lw];
            float4 t3 = wbW[4 * q + 3][lw];
            float4 t4 = wbW[4 * q + 4][lw];
            float4 t5 = wbW[4 * q + 5][lw];
            float4 t6 = wbW[4 * q + 6][lw];
            float4 t7 = wbW[4 * q + 7][lw];
            float4 t8 = wbW[4 * q + 8][lw];
            float4 t9 = wbW[4 * q + 9][lw];
            float4 va = blur7(t0, t1, t2, t3, t4, t5, t6);
            float4 vb = blur7(t1, t2, t3, t4, t5, t6, t7);
            float4 vc = blur7(t2, t3, t4, t5, t6, t7, t8);
            float4 vd = blur7(t3, t4, t5, t6, t7, t8, t9);
            qa0=qa1; qa1=qa2; qa2=qa3; qa3=qa4; qa4=qa5; qa5=qa6; qa6=va;
            qb0=qb1; qb1=qb2; qb2=qb3; qb3=qb4; qb4=qb5; qb5=qb6; qb6=vb;
            qc0=qc1; qc1=qc2; qc2=qc3; qc3=qc4; qc4=qc5; qc5=qc6; qc6=vc;
            qd0=qd1; qd1=qd2; qd2=qd3; qd3=qd4; qd4=qd5; qd5=qd6; qd6=vd;
        }

        // 5) emit 4 output rows for dout = din-3 once rings are primed
        if (k >= 6) {
            const int dout = din - 3;
            float4 oa = blur7(qa0, qa1, qa2, qa3, qa4, qa5, qa6);
            float4 ob = blur7(qb0, qb1, qb2, qb3, qb4, qb5, qb6);
            float4 oc = blur7(qc0, qc1, qc2, qc3, qc4, qc5, qc6);
            float4 od = blur7(qd0, qd1, qd2, qd3, qd4, qd5, qd6);
            const size_t base = nbase + (size_t)dout * SLICE + (size_t)(h0 + 4 * q) * DIM + (w0 + lw);
            out[base + 0 * DIM] = oa;
            out[base + 1 * DIM] = ob;
            out[base + 2 * DIM] = oc;
            out[base + 3 * DIM] = od;
        }
    }
#undef PREFETCH
#undef WGRP
}

extern "C" void kernel_launch(void* const* d_in, const int* in_sizes, int n_in,
                              void* d_out, int out_size, void* d_ws, size_t ws_size,
                              hipStream_t stream) {
    const float4* in = (const float4*)d_in[0];
    float4* out = (float4*)d_out;
    gauss3d_fused<<<NBLK, 256, 0, stream>>>(in, out);
}